// Round 1
// baseline (620.601 us; speedup 1.0000x reference)
//
#include <hip/hip_runtime.h>

#define NN 50000
#define NE 800000
#define FIN 512
#define FHID 256
#define FOUT 128

// ---------------- CSR build ----------------

__global__ __launch_bounds__(256) void zero_int_kernel(int* __restrict__ p, int n) {
    int i = blockIdx.x * 256 + threadIdx.x;
    if (i < n) p[i] = 0;
}

__global__ __launch_bounds__(256) void count_deg_kernel(const int* __restrict__ dst,
                                                        int* __restrict__ deg) {
    int e = blockIdx.x * 256 + threadIdx.x;
    if (e < NE) atomicAdd(&deg[dst[e]], 1);
}

// Single-block exclusive scan of deg[0..NN-1] -> off[0..NN], also leaves the
// same exclusive prefix in `cur` (the scatter cursor). deg lives in `cur` on
// entry and is overwritten (read-before-write within each chunk).
__global__ __launch_bounds__(1024) void scan_kernel(int* __restrict__ cur,
                                                    int* __restrict__ off) {
    __shared__ int sh[1024];
    __shared__ int s_run;
    int tid = threadIdx.x;
    if (tid == 0) s_run = 0;
    __syncthreads();
    for (int base = 0; base < NN; base += 1024) {
        int i = base + tid;
        int v = (i < NN) ? cur[i] : 0;
        sh[tid] = v;
        __syncthreads();
        for (int s = 1; s < 1024; s <<= 1) {
            int t = (tid >= s) ? sh[tid - s] : 0;
            __syncthreads();
            sh[tid] += t;
            __syncthreads();
        }
        int incl = sh[tid];
        int run  = s_run;
        if (i < NN) {
            off[i] = run + incl - v;
            cur[i] = run + incl - v;
        }
        __syncthreads();
        if (tid == 0) s_run = run + sh[1023];
        __syncthreads();
    }
    if (tid == 0) off[NN] = s_run;
}

__global__ __launch_bounds__(256) void scatter_kernel(const int* __restrict__ src,
                                                      const int* __restrict__ dst,
                                                      const float* __restrict__ w,
                                                      int* __restrict__ cur,
                                                      int* __restrict__ csr_src,
                                                      float* __restrict__ csr_w) {
    int e = blockIdx.x * 256 + threadIdx.x;
    if (e < NE) {
        int d = dst[e];
        int p = atomicAdd(&cur[d], 1);
        csr_src[p] = src[e];
        csr_w[p]   = w[e];
    }
}

// ---------------- dense GEMM (f32, LDS-tiled 64x64x16, 4x4 per thread) ----------------

__global__ __launch_bounds__(256) void gemm_f32_kernel(const float* __restrict__ A,
                                                       const float* __restrict__ B,
                                                       float* __restrict__ C,
                                                       int M, int N, int K) {
    __shared__ float As[16][64];  // transposed A tile: As[k][m]
    __shared__ float Bs[16][64];  // Bs[k][n]

    int tid = threadIdx.x;
    int tx  = tid & 15;   // 0..15 -> n groups of 4
    int ty  = tid >> 4;   // 0..15 -> m groups of 4
    int block_row = blockIdx.x * 64;
    int block_col = blockIdx.y * 64;

    int a_row = tid >> 2;         // 0..63
    int a_col = (tid & 3) * 4;    // 0,4,8,12
    int b_row = tid >> 4;         // 0..15
    int b_col = (tid & 15) * 4;   // 0..60

    float acc[4][4] = {};

    for (int k0 = 0; k0 < K; k0 += 16) {
        float4 av = make_float4(0.f, 0.f, 0.f, 0.f);
        int gr = block_row + a_row;
        if (gr < M) av = *(const float4*)(A + (size_t)gr * K + k0 + a_col);
        As[a_col + 0][a_row] = av.x;
        As[a_col + 1][a_row] = av.y;
        As[a_col + 2][a_row] = av.z;
        As[a_col + 3][a_row] = av.w;

        float4 bv = *(const float4*)(B + (size_t)(k0 + b_row) * N + block_col + b_col);
        *(float4*)&Bs[b_row][b_col] = bv;
        __syncthreads();

#pragma unroll
        for (int k = 0; k < 16; ++k) {
            float4 a4 = *(const float4*)&As[k][ty * 4];
            float4 b4 = *(const float4*)&Bs[k][tx * 4];
            float a[4] = {a4.x, a4.y, a4.z, a4.w};
            float b[4] = {b4.x, b4.y, b4.z, b4.w};
#pragma unroll
            for (int m = 0; m < 4; ++m)
#pragma unroll
                for (int n = 0; n < 4; ++n) acc[m][n] += a[m] * b[n];
        }
        __syncthreads();
    }

#pragma unroll
    for (int m = 0; m < 4; ++m) {
        int gr = block_row + ty * 4 + m;
        if (gr < M) {
            float4 v = make_float4(acc[m][0], acc[m][1], acc[m][2], acc[m][3]);
            *(float4*)(C + (size_t)gr * N + block_col + tx * 4) = v;
        }
    }
}

// ---------------- pull-SpMM: one wave per node ----------------

template <int F, bool RELU>
__global__ __launch_bounds__(256) void spmm_kernel(const float* __restrict__ X,
                                                   const int* __restrict__ off,
                                                   const int* __restrict__ csr_src,
                                                   const float* __restrict__ csr_w,
                                                   float* __restrict__ Y) {
    int gw   = (int)((blockIdx.x * 256 + threadIdx.x) >> 6);  // global wave = node
    int lane = threadIdx.x & 63;
    if (gw >= NN) return;
    int e0 = off[gw];
    int e1 = off[gw + 1];

    if constexpr (F == 256) {
        float4 acc = make_float4(0.f, 0.f, 0.f, 0.f);
        for (int e = e0; e < e1; ++e) {
            int   s = csr_src[e];
            float w = csr_w[e];
            float4 r = *(const float4*)(X + (size_t)s * F + lane * 4);
            acc.x += w * r.x; acc.y += w * r.y; acc.z += w * r.z; acc.w += w * r.w;
        }
        if (RELU) {
            acc.x = fmaxf(acc.x, 0.f); acc.y = fmaxf(acc.y, 0.f);
            acc.z = fmaxf(acc.z, 0.f); acc.w = fmaxf(acc.w, 0.f);
        }
        *(float4*)(Y + (size_t)gw * F + lane * 4) = acc;
    } else {
        float2 acc = make_float2(0.f, 0.f);
        for (int e = e0; e < e1; ++e) {
            int   s = csr_src[e];
            float w = csr_w[e];
            float2 r = *(const float2*)(X + (size_t)s * F + lane * 2);
            acc.x += w * r.x; acc.y += w * r.y;
        }
        if (RELU) { acc.x = fmaxf(acc.x, 0.f); acc.y = fmaxf(acc.y, 0.f); }
        *(float2*)(Y + (size_t)gw * F + lane * 2) = acc;
    }
}

// ---------------- launch ----------------

extern "C" void kernel_launch(void* const* d_in, const int* in_sizes, int n_in,
                              void* d_out, int out_size, void* d_ws, size_t ws_size,
                              hipStream_t stream) {
    const float* features = (const float*)d_in[0];
    const int*   edge_src = (const int*)d_in[1];
    const int*   edge_dst = (const int*)d_in[2];
    const float* edge_w   = (const float*)d_in[3];
    const float* W1       = (const float*)d_in[4];
    const float* W2       = (const float*)d_in[5];
    float* out = (float*)d_out;

    char*  ws  = (char*)d_ws;
    size_t ofs = 0;
    auto carve = [&](size_t bytes) -> void* {
        void* r = ws + ofs;
        ofs = (ofs + bytes + 255) & ~(size_t)255;
        return r;
    };
    int*   off   = (int*)carve((NN + 1) * sizeof(int));
    int*   cur   = (int*)carve(NN * sizeof(int));
    int*   csr_s = (int*)carve(NE * sizeof(int));
    float* csr_w = (float*)carve(NE * sizeof(float));
    float* H0    = (float*)carve((size_t)NN * FHID * sizeof(float));
    float* hid   = (float*)carve((size_t)NN * FHID * sizeof(float));
    float* H1    = H0;  // reuse: H0 is dead after spmm1

    // CSR build (reused by both SpMM layers)
    zero_int_kernel<<<(NN + 255) / 256, 256, 0, stream>>>(cur, NN);
    count_deg_kernel<<<(NE + 255) / 256, 256, 0, stream>>>(edge_dst, cur);
    scan_kernel<<<1, 1024, 0, stream>>>(cur, off);
    scatter_kernel<<<(NE + 255) / 256, 256, 0, stream>>>(edge_src, edge_dst, edge_w,
                                                         cur, csr_s, csr_w);

    // layer 1: H0 = X @ W1 ; hid = relu(A @ H0)
    gemm_f32_kernel<<<dim3((NN + 63) / 64, FHID / 64), 256, 0, stream>>>(
        features, W1, H0, NN, FHID, FIN);
    spmm_kernel<FHID, true><<<(NN + 3) / 4, 256, 0, stream>>>(H0, off, csr_s, csr_w, hid);

    // layer 2: H1 = hid @ W2 ; out = A @ H1
    gemm_f32_kernel<<<dim3((NN + 63) / 64, FOUT / 64), 256, 0, stream>>>(
        hid, W2, H1, NN, FOUT, FHID);
    spmm_kernel<FOUT, false><<<(NN + 3) / 4, 256, 0, stream>>>(H1, off, csr_s, csr_w, out);
}

// Round 2
// 375.173 us; speedup vs baseline: 1.6542x; 1.6542x over previous
//
#include <hip/hip_runtime.h>

#define NN 50000
#define NE 800000
#define FIN 512
#define FHID 256
#define FOUT 128
#define MPAD 50048  // 391 * 128

using bf16x8 = __attribute__((ext_vector_type(8))) short;
using f32x4  = __attribute__((ext_vector_type(4))) float;
using u16x8  = __attribute__((ext_vector_type(8))) unsigned short;
using u16x4  = __attribute__((ext_vector_type(4))) unsigned short;
using u16x2  = __attribute__((ext_vector_type(2))) unsigned short;

__device__ __forceinline__ unsigned short f2bf(float f) {
    unsigned int u = __builtin_bit_cast(unsigned int, f);
    unsigned int r = (u + 0x7FFFu + ((u >> 16) & 1u)) >> 16;   // RNE
    return (unsigned short)r;
}
__device__ __forceinline__ float bf2f(unsigned short u) {
    return __builtin_bit_cast(float, (unsigned int)u << 16);
}
__device__ __forceinline__ void gload_lds16(const void* g, void* l) {
    __builtin_amdgcn_global_load_lds(
        (const __attribute__((address_space(1))) void*)g,
        (__attribute__((address_space(3))) void*)l, 16, 0, 0);
}

// ---------------- CSR build ----------------

__global__ __launch_bounds__(256) void zero_int_kernel(int* __restrict__ p, int n) {
    int i = blockIdx.x * 256 + threadIdx.x;
    if (i < n) p[i] = 0;
}

__global__ __launch_bounds__(256) void count_deg_kernel(const int* __restrict__ dst,
                                                        int* __restrict__ deg) {
    int e = blockIdx.x * 256 + threadIdx.x;
    if (e < NE) atomicAdd(&deg[dst[e]], 1);
}

// Single-block exclusive scan: wave shfl-scan + cross-wave LDS (2 barriers/chunk).
__global__ __launch_bounds__(1024) void scan_kernel(int* __restrict__ cur,
                                                    int* __restrict__ off) {
    __shared__ int wsum[16];
    __shared__ int s_run;
    int tid = threadIdx.x, lane = tid & 63, wid = tid >> 6;
    if (tid == 0) s_run = 0;
    __syncthreads();
    for (int base = 0; base < NN; base += 1024) {
        int i  = base + tid;
        int v0 = (i < NN) ? cur[i] : 0;
        int v  = v0;
#pragma unroll
        for (int d = 1; d < 64; d <<= 1) {
            int t = __shfl_up(v, d, 64);
            if (lane >= d) v += t;
        }
        if (lane == 63) wsum[wid] = v;
        __syncthreads();
        int run = s_run, wpre = 0, tot = 0;
#pragma unroll
        for (int j = 0; j < 16; ++j) {
            int s = wsum[j];
            if (j < wid) wpre += s;
            tot += s;
        }
        int excl = run + wpre + v - v0;
        if (i < NN) { off[i] = excl; cur[i] = excl; }
        __syncthreads();
        if (tid == 0) s_run = run + tot;
        // next-iteration's first __syncthreads orders this store before reads
    }
    __syncthreads();
    if (tid == 0) off[NN] = s_run;
}

__global__ __launch_bounds__(256) void scatter_kernel(const int* __restrict__ src,
                                                      const int* __restrict__ dst,
                                                      const float* __restrict__ w,
                                                      int* __restrict__ cur,
                                                      int* __restrict__ csr_src,
                                                      float* __restrict__ csr_w) {
    int e = blockIdx.x * 256 + threadIdx.x;
    if (e < NE) {
        int d = dst[e];
        int p = atomicAdd(&cur[d], 1);
        csr_src[p] = src[e];
        csr_w[p]   = w[e];
    }
}

// ---------------- casts ----------------

__global__ __launch_bounds__(256) void cast_f32_bf16_kernel(const float* __restrict__ X,
                                                            unsigned short* __restrict__ Y,
                                                            int n8) {
    int i = blockIdx.x * 256 + threadIdx.x;
    if (i >= n8) return;
    const float4* p = (const float4*)X + (size_t)i * 2;
    float4 a = p[0], b = p[1];
    u16x8 v;
    v[0] = f2bf(a.x); v[1] = f2bf(a.y); v[2] = f2bf(a.z); v[3] = f2bf(a.w);
    v[4] = f2bf(b.x); v[5] = f2bf(b.y); v[6] = f2bf(b.z); v[7] = f2bf(b.w);
    *(u16x8*)(Y + (size_t)i * 8) = v;
}

template <int K, int N>
__global__ __launch_bounds__(256) void transpose_cast_kernel(const float* __restrict__ W,
                                                             unsigned short* __restrict__ WT) {
    int t = blockIdx.x * 256 + threadIdx.x;
    if (t >= K * N) return;
    int n = t % N, k = t / N;
    WT[(size_t)n * K + k] = f2bf(W[t]);
}

// ---------------- bf16 MFMA GEMM: C[M][N] = A[M][K] @ BT[N][K]^T ----------------
// 128x128 tile, BK=64, 4 waves (2x2), 16x16x32 MFMA, global_load_lds staging
// with XOR swizzle (byte ^= (row&7)<<4) applied on the global SOURCE address
// (LDS dest linear) and re-applied on the ds_read side.

template <int K, int N>
__global__ __launch_bounds__(256) void gemm_bf16_kernel(const unsigned short* __restrict__ A,
                                                        const unsigned short* __restrict__ BT,
                                                        unsigned short* __restrict__ C,
                                                        int M) {
    __shared__ unsigned short As[128 * 64];
    __shared__ unsigned short Bs[128 * 64];

    const int tid  = threadIdx.x;
    const int lane = tid & 63;
    const int wid  = tid >> 6;
    const int wm   = wid >> 1;
    const int wn   = wid & 1;
    const int brow = blockIdx.x * 128;
    const int bcol = blockIdx.y * 128;
    const int r15   = lane & 15;
    const int khalf = (lane >> 4) * 8;

    f32x4 acc[4][4] = {};

    for (int k0 = 0; k0 < K; k0 += 64) {
        // ---- stage A and B tiles (each wave: 4x1KB chunks of each) ----
#pragma unroll
        for (int c = 0; c < 4; ++c) {
            int b   = wid * 4096 + c * 1024 + lane * 16;
            int row = b >> 7;
            int cby = (b & 127) ^ ((row & 7) << 4);
            const char* ga = (const char*)(A + (size_t)(brow + row) * K + k0) + cby;
            gload_lds16(ga, (char*)As + wid * 4096 + c * 1024);
            const char* gb = (const char*)(BT + (size_t)(bcol + row) * K + k0) + cby;
            gload_lds16(gb, (char*)Bs + wid * 4096 + c * 1024);
        }
        __syncthreads();

        // ---- fragments ----
        bf16x8 af[4][2], bfr[4][2];
#pragma unroll
        for (int m = 0; m < 4; ++m) {
            int row = wm * 64 + m * 16 + r15;
            int rb  = row * 128;
            int sw  = (row & 7) << 4;
#pragma unroll
            for (int ks = 0; ks < 2; ++ks) {
                int byte = rb + (((ks * 32 + khalf) * 2) ^ sw);
                af[m][ks] = *(const bf16x8*)((const char*)As + byte);
            }
        }
#pragma unroll
        for (int n = 0; n < 4; ++n) {
            int row = wn * 64 + n * 16 + r15;
            int rb  = row * 128;
            int sw  = (row & 7) << 4;
#pragma unroll
            for (int ks = 0; ks < 2; ++ks) {
                int byte = rb + (((ks * 32 + khalf) * 2) ^ sw);
                bfr[n][ks] = *(const bf16x8*)((const char*)Bs + byte);
            }
        }
#pragma unroll
        for (int m = 0; m < 4; ++m)
#pragma unroll
            for (int n = 0; n < 4; ++n)
#pragma unroll
                for (int ks = 0; ks < 2; ++ks)
                    acc[m][n] = __builtin_amdgcn_mfma_f32_16x16x32_bf16(
                        af[m][ks], bfr[n][ks], acc[m][n], 0, 0, 0);
        __syncthreads();
    }

    // ---- epilogue: C/D layout col=lane&15, row=(lane>>4)*4+reg ----
    const int crow0 = brow + wm * 64;
    const int ccol0 = bcol + wn * 64 + r15;
    const int rsub  = (lane >> 4) * 4;
#pragma unroll
    for (int m = 0; m < 4; ++m) {
#pragma unroll
        for (int r = 0; r < 4; ++r) {
            int grow = crow0 + m * 16 + rsub + r;
            if (grow < M) {
#pragma unroll
                for (int n = 0; n < 4; ++n)
                    C[(size_t)grow * N + ccol0 + n * 16] = f2bf(acc[m][n][r]);
            }
        }
    }
}

// ---------------- pull-SpMM: one wave per node, bf16 gather ----------------

template <int F, bool RELU, bool OUTBF>
__global__ __launch_bounds__(256) void spmm_kernel(const unsigned short* __restrict__ X,
                                                   const int* __restrict__ off,
                                                   const int* __restrict__ csr_src,
                                                   const float* __restrict__ csr_w,
                                                   void* __restrict__ Yv) {
    int gw   = (int)((blockIdx.x * 256 + threadIdx.x) >> 6);
    int lane = threadIdx.x & 63;
    if (gw >= NN) return;
    int e0 = off[gw];
    int e1 = off[gw + 1];

    if constexpr (F == 256) {
        float acc0 = 0.f, acc1 = 0.f, acc2 = 0.f, acc3 = 0.f;
        const size_t lo = (size_t)lane * 4;
        for (int e = e0; e < e1; ++e) {
            int   s = csr_src[e];
            float w = csr_w[e];
            u16x4 r = *(const u16x4*)(X + (size_t)s * F + lo);
            acc0 += w * bf2f(r[0]); acc1 += w * bf2f(r[1]);
            acc2 += w * bf2f(r[2]); acc3 += w * bf2f(r[3]);
        }
        if (RELU) {
            acc0 = fmaxf(acc0, 0.f); acc1 = fmaxf(acc1, 0.f);
            acc2 = fmaxf(acc2, 0.f); acc3 = fmaxf(acc3, 0.f);
        }
        u16x4 o;
        o[0] = f2bf(acc0); o[1] = f2bf(acc1); o[2] = f2bf(acc2); o[3] = f2bf(acc3);
        *(u16x4*)((unsigned short*)Yv + (size_t)gw * F + lo) = o;
    } else {  // F == 128
        float acc0 = 0.f, acc1 = 0.f;
        const size_t lo = (size_t)lane * 2;
        for (int e = e0; e < e1; ++e) {
            int   s = csr_src[e];
            float w = csr_w[e];
            u16x2 r = *(const u16x2*)(X + (size_t)s * F + lo);
            acc0 += w * bf2f(r[0]); acc1 += w * bf2f(r[1]);
        }
        if (RELU) { acc0 = fmaxf(acc0, 0.f); acc1 = fmaxf(acc1, 0.f); }
        float2 o = make_float2(acc0, acc1);
        *(float2*)((float*)Yv + (size_t)gw * F + lo) = o;
    }
}

// ---------------- launch ----------------

extern "C" void kernel_launch(void* const* d_in, const int* in_sizes, int n_in,
                              void* d_out, int out_size, void* d_ws, size_t ws_size,
                              hipStream_t stream) {
    const float* features = (const float*)d_in[0];
    const int*   edge_src = (const int*)d_in[1];
    const int*   edge_dst = (const int*)d_in[2];
    const float* edge_w   = (const float*)d_in[3];
    const float* W1       = (const float*)d_in[4];
    const float* W2       = (const float*)d_in[5];
    float* out = (float*)d_out;

    char*  ws  = (char*)d_ws;
    size_t ofs = 0;
    auto carve = [&](size_t bytes) -> void* {
        void* r = ws + ofs;
        ofs = (ofs + bytes + 255) & ~(size_t)255;
        return r;
    };
    int*            off   = (int*)carve((NN + 1) * sizeof(int));
    int*            cur   = (int*)carve(NN * sizeof(int));
    int*            csr_s = (int*)carve(NE * sizeof(int));
    float*          csr_w = (float*)carve(NE * sizeof(float));
    unsigned short* Xb    = (unsigned short*)carve((size_t)MPAD * FIN * 2);
    unsigned short* W1T   = (unsigned short*)carve((size_t)FHID * FIN * 2);
    unsigned short* W2T   = (unsigned short*)carve((size_t)FOUT * FHID * 2);
    unsigned short* H0b   = (unsigned short*)carve((size_t)MPAD * FHID * 2);
    unsigned short* Hb    = (unsigned short*)carve((size_t)MPAD * FHID * 2);
    unsigned short* H1b   = H0b;  // H0b dead after spmm1

    // CSR build (reused by both SpMM layers)
    zero_int_kernel<<<(NN + 255) / 256, 256, 0, stream>>>(cur, NN);
    count_deg_kernel<<<(NE + 255) / 256, 256, 0, stream>>>(edge_dst, cur);
    scan_kernel<<<1, 1024, 0, stream>>>(cur, off);
    scatter_kernel<<<(NE + 255) / 256, 256, 0, stream>>>(edge_src, edge_dst, edge_w,
                                                         cur, csr_s, csr_w);

    // casts
    cast_f32_bf16_kernel<<<(NN * FIN / 8 + 255) / 256, 256, 0, stream>>>(
        features, Xb, NN * FIN / 8);
    transpose_cast_kernel<FIN, FHID><<<(FIN * FHID + 255) / 256, 256, 0, stream>>>(W1, W1T);
    transpose_cast_kernel<FHID, FOUT><<<(FHID * FOUT + 255) / 256, 256, 0, stream>>>(W2, W2T);

    // layer 1: H0 = X @ W1 ; hidden = relu(A @ H0)  (hidden stored bf16)
    gemm_bf16_kernel<FIN, FHID><<<dim3(MPAD / 128, FHID / 128), 256, 0, stream>>>(
        Xb, W1T, H0b, NN);
    spmm_kernel<FHID, true, true><<<(NN * 64 + 255) / 256, 256, 0, stream>>>(
        H0b, off, csr_s, csr_w, Hb);

    // layer 2: H1 = hidden @ W2 ; out = A @ H1
    gemm_bf16_kernel<FHID, FOUT><<<dim3(MPAD / 128, FOUT / 128), 256, 0, stream>>>(
        Hb, W2T, H1b, NN);
    spmm_kernel<FOUT, false, false><<<(NN * 64 + 255) / 256, 256, 0, stream>>>(
        H1b, off, csr_s, csr_w, out);
}

// Round 3
// 296.183 us; speedup vs baseline: 2.0953x; 1.2667x over previous
//
#include <hip/hip_runtime.h>

#define NN 50000
#define NE 800000
#define FIN 512
#define FHID 256
#define FOUT 128
#define MPAD 50048  // 391 * 128

using bf16x8 = __attribute__((ext_vector_type(8))) short;
using f32x4  = __attribute__((ext_vector_type(4))) float;
using u16x8  = __attribute__((ext_vector_type(8))) unsigned short;
using u16x4  = __attribute__((ext_vector_type(4))) unsigned short;
using u16x2  = __attribute__((ext_vector_type(2))) unsigned short;

__device__ __forceinline__ unsigned short f2bf(float f) {
    unsigned int u = __builtin_bit_cast(unsigned int, f);
    unsigned int r = (u + 0x7FFFu + ((u >> 16) & 1u)) >> 16;   // RNE
    return (unsigned short)r;
}
__device__ __forceinline__ float bf2f(unsigned short u) {
    return __builtin_bit_cast(float, (unsigned int)u << 16);
}
__device__ __forceinline__ void gload_lds16(const void* g, void* l) {
    __builtin_amdgcn_global_load_lds(
        (const __attribute__((address_space(1))) void*)g,
        (__attribute__((address_space(3))) void*)l, 16, 0, 0);
}

// ---------------- CSR build ----------------

__global__ __launch_bounds__(256) void zero_int_kernel(int* __restrict__ p, int n) {
    int i = blockIdx.x * 256 + threadIdx.x;
    if (i < n) p[i] = 0;
}

__global__ __launch_bounds__(256) void count_deg_kernel(const int* __restrict__ dst,
                                                        int* __restrict__ deg) {
    int e = blockIdx.x * 256 + threadIdx.x;
    if (e < NE) atomicAdd(&deg[dst[e]], 1);
}

// Single-block exclusive scan: wave shfl-scan + cross-wave LDS (2 barriers/chunk).
__global__ __launch_bounds__(1024) void scan_kernel(int* __restrict__ cur,
                                                    int* __restrict__ off) {
    __shared__ int wsum[16];
    __shared__ int s_run;
    int tid = threadIdx.x, lane = tid & 63, wid = tid >> 6;
    if (tid == 0) s_run = 0;
    __syncthreads();
    for (int base = 0; base < NN; base += 1024) {
        int i  = base + tid;
        int v0 = (i < NN) ? cur[i] : 0;
        int v  = v0;
#pragma unroll
        for (int d = 1; d < 64; d <<= 1) {
            int t = __shfl_up(v, d, 64);
            if (lane >= d) v += t;
        }
        if (lane == 63) wsum[wid] = v;
        __syncthreads();
        int run = s_run, wpre = 0, tot = 0;
#pragma unroll
        for (int j = 0; j < 16; ++j) {
            int s = wsum[j];
            if (j < wid) wpre += s;
            tot += s;
        }
        int excl = run + wpre + v - v0;
        if (i < NN) { off[i] = excl; cur[i] = excl; }
        __syncthreads();
        if (tid == 0) s_run = run + tot;
        // next-iteration's first __syncthreads orders this store before reads
    }
    __syncthreads();
    if (tid == 0) off[NN] = s_run;
}

__global__ __launch_bounds__(256) void scatter_kernel(const int* __restrict__ src,
                                                      const int* __restrict__ dst,
                                                      const float* __restrict__ w,
                                                      int* __restrict__ cur,
                                                      int* __restrict__ csr_src,
                                                      float* __restrict__ csr_w) {
    int e = blockIdx.x * 256 + threadIdx.x;
    if (e < NE) {
        int d = dst[e];
        int p = atomicAdd(&cur[d], 1);
        csr_src[p] = src[e];
        csr_w[p]   = w[e];
    }
}

// ---------------- casts ----------------

__global__ __launch_bounds__(256) void cast_f32_bf16_kernel(const float* __restrict__ X,
                                                            unsigned short* __restrict__ Y,
                                                            int n8) {
    int i = blockIdx.x * 256 + threadIdx.x;
    if (i >= n8) return;
    const float4* p = (const float4*)X + (size_t)i * 2;
    float4 a = p[0], b = p[1];
    u16x8 v;
    v[0] = f2bf(a.x); v[1] = f2bf(a.y); v[2] = f2bf(a.z); v[3] = f2bf(a.w);
    v[4] = f2bf(b.x); v[5] = f2bf(b.y); v[6] = f2bf(b.z); v[7] = f2bf(b.w);
    *(u16x8*)(Y + (size_t)i * 8) = v;
}

template <int K, int N>
__global__ __launch_bounds__(256) void transpose_cast_kernel(const float* __restrict__ W,
                                                             unsigned short* __restrict__ WT) {
    int t = blockIdx.x * 256 + threadIdx.x;
    if (t >= K * N) return;
    int n = t % N, k = t / N;
    WT[(size_t)n * K + k] = f2bf(W[t]);
}

// ---------------- bf16 MFMA GEMM: C[M][N] = A[M][K] @ BT[N][K]^T ----------------
// 128x128 tile, BK=64, 4 waves (2x2), 16x16x32 MFMA, global_load_lds staging
// with XOR swizzle (byte ^= (row&7)<<4) applied on the global SOURCE address
// (LDS dest linear) and re-applied on the ds_read side.

template <int K, int N>
__global__ __launch_bounds__(256) void gemm_bf16_kernel(const unsigned short* __restrict__ A,
                                                        const unsigned short* __restrict__ BT,
                                                        unsigned short* __restrict__ C,
                                                        int M) {
    __shared__ unsigned short As[128 * 64];
    __shared__ unsigned short Bs[128 * 64];

    const int tid  = threadIdx.x;
    const int lane = tid & 63;
    const int wid  = tid >> 6;
    const int wm   = wid >> 1;
    const int wn   = wid & 1;
    const int brow = blockIdx.x * 128;
    const int bcol = blockIdx.y * 128;
    const int r15   = lane & 15;
    const int khalf = (lane >> 4) * 8;

    f32x4 acc[4][4] = {};

    for (int k0 = 0; k0 < K; k0 += 64) {
        // ---- stage A and B tiles (each wave: 4x1KB chunks of each) ----
#pragma unroll
        for (int c = 0; c < 4; ++c) {
            int b   = wid * 4096 + c * 1024 + lane * 16;
            int row = b >> 7;
            int cby = (b & 127) ^ ((row & 7) << 4);
            const char* ga = (const char*)(A + (size_t)(brow + row) * K + k0) + cby;
            gload_lds16(ga, (char*)As + wid * 4096 + c * 1024);
            const char* gb = (const char*)(BT + (size_t)(bcol + row) * K + k0) + cby;
            gload_lds16(gb, (char*)Bs + wid * 4096 + c * 1024);
        }
        __syncthreads();

        // ---- fragments ----
        bf16x8 af[4][2], bfr[4][2];
#pragma unroll
        for (int m = 0; m < 4; ++m) {
            int row = wm * 64 + m * 16 + r15;
            int rb  = row * 128;
            int sw  = (row & 7) << 4;
#pragma unroll
            for (int ks = 0; ks < 2; ++ks) {
                int byte = rb + (((ks * 32 + khalf) * 2) ^ sw);
                af[m][ks] = *(const bf16x8*)((const char*)As + byte);
            }
        }
#pragma unroll
        for (int n = 0; n < 4; ++n) {
            int row = wn * 64 + n * 16 + r15;
            int rb  = row * 128;
            int sw  = (row & 7) << 4;
#pragma unroll
            for (int ks = 0; ks < 2; ++ks) {
                int byte = rb + (((ks * 32 + khalf) * 2) ^ sw);
                bfr[n][ks] = *(const bf16x8*)((const char*)Bs + byte);
            }
        }
#pragma unroll
        for (int m = 0; m < 4; ++m)
#pragma unroll
            for (int n = 0; n < 4; ++n)
#pragma unroll
                for (int ks = 0; ks < 2; ++ks)
                    acc[m][n] = __builtin_amdgcn_mfma_f32_16x16x32_bf16(
                        af[m][ks], bfr[n][ks], acc[m][n], 0, 0, 0);
        __syncthreads();
    }

    // ---- epilogue: C/D layout col=lane&15, row=(lane>>4)*4+reg ----
    const int crow0 = brow + wm * 64;
    const int ccol0 = bcol + wn * 64 + r15;
    const int rsub  = (lane >> 4) * 4;
#pragma unroll
    for (int m = 0; m < 4; ++m) {
#pragma unroll
        for (int r = 0; r < 4; ++r) {
            int grow = crow0 + m * 16 + rsub + r;
            if (grow < M) {
#pragma unroll
                for (int n = 0; n < 4; ++n)
                    C[(size_t)grow * N + ccol0 + n * 16] = f2bf(acc[m][n][r]);
            }
        }
    }
}

// ---------------- pull-SpMM: one wave per node, 8-wide predicated edge unroll ----------------
// Tail edges are padded in-register: index clamped to e0 (always valid), weight
// forced to 0 -> every chunk issues 8 independent gathers (full MLP, no remainder).

template <int F, bool RELU, bool OUTBF>
__global__ __launch_bounds__(256) void spmm_kernel(const unsigned short* __restrict__ X,
                                                   const int* __restrict__ off,
                                                   const int* __restrict__ csr_src,
                                                   const float* __restrict__ csr_w,
                                                   void* __restrict__ Yv) {
    int gw   = (int)((blockIdx.x * 256 + threadIdx.x) >> 6);
    int lane = threadIdx.x & 63;
    if (gw >= NN) return;
    int e0 = off[gw];
    int e1 = off[gw + 1];

    if constexpr (F == 256) {
        float acc0 = 0.f, acc1 = 0.f, acc2 = 0.f, acc3 = 0.f;
        const size_t lo = (size_t)lane * 4;
        for (int e = e0; e < e1; e += 8) {
            int   ss[8];
            float ww[8];
#pragma unroll
            for (int j = 0; j < 8; ++j) {
                int  ee = e + j;
                bool v  = ee < e1;
                int  ec = v ? ee : e0;
                ss[j] = csr_src[ec];
                float wv = csr_w[ec];
                ww[j] = v ? wv : 0.f;
            }
            u16x4 r[8];
#pragma unroll
            for (int j = 0; j < 8; ++j)
                r[j] = *(const u16x4*)(X + (size_t)ss[j] * F + lo);
#pragma unroll
            for (int j = 0; j < 8; ++j) {
                acc0 += ww[j] * bf2f(r[j][0]);
                acc1 += ww[j] * bf2f(r[j][1]);
                acc2 += ww[j] * bf2f(r[j][2]);
                acc3 += ww[j] * bf2f(r[j][3]);
            }
        }
        if (RELU) {
            acc0 = fmaxf(acc0, 0.f); acc1 = fmaxf(acc1, 0.f);
            acc2 = fmaxf(acc2, 0.f); acc3 = fmaxf(acc3, 0.f);
        }
        u16x4 o;
        o[0] = f2bf(acc0); o[1] = f2bf(acc1); o[2] = f2bf(acc2); o[3] = f2bf(acc3);
        *(u16x4*)((unsigned short*)Yv + (size_t)gw * F + lo) = o;
    } else {  // F == 128
        float acc0 = 0.f, acc1 = 0.f;
        const size_t lo = (size_t)lane * 2;
        for (int e = e0; e < e1; e += 8) {
            int   ss[8];
            float ww[8];
#pragma unroll
            for (int j = 0; j < 8; ++j) {
                int  ee = e + j;
                bool v  = ee < e1;
                int  ec = v ? ee : e0;
                ss[j] = csr_src[ec];
                float wv = csr_w[ec];
                ww[j] = v ? wv : 0.f;
            }
            u16x2 r[8];
#pragma unroll
            for (int j = 0; j < 8; ++j)
                r[j] = *(const u16x2*)(X + (size_t)ss[j] * F + lo);
#pragma unroll
            for (int j = 0; j < 8; ++j) {
                acc0 += ww[j] * bf2f(r[j][0]);
                acc1 += ww[j] * bf2f(r[j][1]);
            }
        }
        if (RELU) { acc0 = fmaxf(acc0, 0.f); acc1 = fmaxf(acc1, 0.f); }
        float2 o = make_float2(acc0, acc1);
        *(float2*)((float*)Yv + (size_t)gw * F + lo) = o;
    }
}

// ---------------- launch ----------------

extern "C" void kernel_launch(void* const* d_in, const int* in_sizes, int n_in,
                              void* d_out, int out_size, void* d_ws, size_t ws_size,
                              hipStream_t stream) {
    const float* features = (const float*)d_in[0];
    const int*   edge_src = (const int*)d_in[1];
    const int*   edge_dst = (const int*)d_in[2];
    const float* edge_w   = (const float*)d_in[3];
    const float* W1       = (const float*)d_in[4];
    const float* W2       = (const float*)d_in[5];
    float* out = (float*)d_out;

    char*  ws  = (char*)d_ws;
    size_t ofs = 0;
    auto carve = [&](size_t bytes) -> void* {
        void* r = ws + ofs;
        ofs = (ofs + bytes + 255) & ~(size_t)255;
        return r;
    };
    int*            off   = (int*)carve((NN + 1) * sizeof(int));
    int*            cur   = (int*)carve(NN * sizeof(int));
    int*            csr_s = (int*)carve(NE * sizeof(int));
    float*          csr_w = (float*)carve(NE * sizeof(float));
    unsigned short* Xb    = (unsigned short*)carve((size_t)MPAD * FIN * 2);
    unsigned short* W1T   = (unsigned short*)carve((size_t)FHID * FIN * 2);
    unsigned short* W2T   = (unsigned short*)carve((size_t)FOUT * FHID * 2);
    unsigned short* H0b   = (unsigned short*)carve((size_t)MPAD * FHID * 2);
    unsigned short* Hb    = (unsigned short*)carve((size_t)MPAD * FHID * 2);
    unsigned short* H1b   = H0b;  // H0b dead after spmm1

    // CSR build (reused by both SpMM layers)
    zero_int_kernel<<<(NN + 255) / 256, 256, 0, stream>>>(cur, NN);
    count_deg_kernel<<<(NE + 255) / 256, 256, 0, stream>>>(edge_dst, cur);
    scan_kernel<<<1, 1024, 0, stream>>>(cur, off);
    scatter_kernel<<<(NE + 255) / 256, 256, 0, stream>>>(edge_src, edge_dst, edge_w,
                                                         cur, csr_s, csr_w);

    // casts
    cast_f32_bf16_kernel<<<(NN * FIN / 8 + 255) / 256, 256, 0, stream>>>(
        features, Xb, NN * FIN / 8);
    transpose_cast_kernel<FIN, FHID><<<(FIN * FHID + 255) / 256, 256, 0, stream>>>(W1, W1T);
    transpose_cast_kernel<FHID, FOUT><<<(FHID * FOUT + 255) / 256, 256, 0, stream>>>(W2, W2T);

    // layer 1: H0 = X @ W1 ; hidden = relu(A @ H0)  (hidden stored bf16)
    gemm_bf16_kernel<FIN, FHID><<<dim3(MPAD / 128, FHID / 128), 256, 0, stream>>>(
        Xb, W1T, H0b, NN);
    spmm_kernel<FHID, true, true><<<(NN * 64 + 255) / 256, 256, 0, stream>>>(
        H0b, off, csr_s, csr_w, Hb);

    // layer 2: H1 = hidden @ W2 ; out = A @ H1
    gemm_bf16_kernel<FHID, FOUT><<<dim3(MPAD / 128, FOUT / 128), 256, 0, stream>>>(
        Hb, W2T, H1b, NN);
    spmm_kernel<FOUT, false, false><<<(NN * 64 + 255) / 256, 256, 0, stream>>>(
        H1b, off, csr_s, csr_w, out);
}

// Round 4
// 258.060 us; speedup vs baseline: 2.4049x; 1.1477x over previous
//
#include <hip/hip_runtime.h>

#define NN 50000
#define NE 800000
#define FIN 512
#define FHID 256
#define FOUT 128
#define MPAD 50048  // 391 * 128

#define CAST_BLOCKS 12500   // NN*FIN/8/256
#define CNT_BLOCKS  782
#define TW1_BLOCKS  512     // FIN*FHID/256
#define TW2_BLOCKS  128     // FHID*FOUT/256
#define ESTRIDE     200192  // CNT_BLOCKS*256 (=SCAT threads); 4*ESTRIDE >= NE

#define GEMM1_BLOCKS 782    // 391 * 2
#define SCAT_BLOCKS  782

#define SNB 49              // ceil(NN/1024)

using bf16x8 = __attribute__((ext_vector_type(8))) short;
using f32x4  = __attribute__((ext_vector_type(4))) float;
using u16x8  = __attribute__((ext_vector_type(8))) unsigned short;
using u16x4  = __attribute__((ext_vector_type(4))) unsigned short;
using u16x2  = __attribute__((ext_vector_type(2))) unsigned short;

__device__ __forceinline__ unsigned short f2bf(float f) {
    unsigned int u = __builtin_bit_cast(unsigned int, f);
    unsigned int r = (u + 0x7FFFu + ((u >> 16) & 1u)) >> 16;   // RNE
    return (unsigned short)r;
}
__device__ __forceinline__ float bf2f(unsigned short u) {
    return __builtin_bit_cast(float, (unsigned int)u << 16);
}
__device__ __forceinline__ void gload_lds16(const void* g, void* l) {
    __builtin_amdgcn_global_load_lds(
        (const __attribute__((address_space(1))) void*)g,
        (__attribute__((address_space(3))) void*)l, 16, 0, 0);
}

// ---------------- fused pre-pass: cast_x || count_deg || transpose W1 || transpose W2 ----

__global__ __launch_bounds__(256) void fused_pre_kernel(
    const float* __restrict__ X, unsigned short* __restrict__ Xb,
    const int* __restrict__ dst, int* __restrict__ deg,
    const float* __restrict__ W1, unsigned short* __restrict__ W1T,
    const float* __restrict__ W2, unsigned short* __restrict__ W2T) {
    int b = blockIdx.x, tid = threadIdx.x;
    if (b < CAST_BLOCKS) {
        int i = b * 256 + tid;  // exact: CAST_BLOCKS*256 == NN*FIN/8
        const float4* p = (const float4*)X + (size_t)i * 2;
        float4 a = p[0], c = p[1];
        u16x8 v;
        v[0] = f2bf(a.x); v[1] = f2bf(a.y); v[2] = f2bf(a.z); v[3] = f2bf(a.w);
        v[4] = f2bf(c.x); v[5] = f2bf(c.y); v[6] = f2bf(c.z); v[7] = f2bf(c.w);
        *(u16x8*)(Xb + (size_t)i * 8) = v;
    } else if (b < CAST_BLOCKS + CNT_BLOCKS) {
        int t  = (b - CAST_BLOCKS) * 256 + tid;
        int e3 = t + 3 * ESTRIDE;
        bool v3 = e3 < NE;   // e0..e2 always < NE
        int d0 = dst[t];
        int d1 = dst[t + ESTRIDE];
        int d2 = dst[t + 2 * ESTRIDE];
        int d3 = v3 ? dst[e3] : 0;
        atomicAdd(&deg[d0], 1);
        atomicAdd(&deg[d1], 1);
        atomicAdd(&deg[d2], 1);
        if (v3) atomicAdd(&deg[d3], 1);
    } else if (b < CAST_BLOCKS + CNT_BLOCKS + TW1_BLOCKS) {
        int t = (b - CAST_BLOCKS - CNT_BLOCKS) * 256 + tid;
        int n = t % FHID, k = t / FHID;
        W1T[(size_t)n * FIN + k] = f2bf(W1[t]);
    } else {
        int t = (b - CAST_BLOCKS - CNT_BLOCKS - TW1_BLOCKS) * 256 + tid;
        int n = t % FOUT, k = t / FOUT;
        W2T[(size_t)n * FHID + k] = f2bf(W2[t]);
    }
}

// ---------------- decoupled 3-pass exclusive scan of deg -> off, cur ----------------

__global__ __launch_bounds__(1024) void scan1_kernel(const int* __restrict__ deg,
                                                     int* __restrict__ bsum) {
    __shared__ int wsum[16];
    int tid = threadIdx.x, lane = tid & 63, wid = tid >> 6;
    int i = blockIdx.x * 1024 + tid;
    int v = (i < NN) ? deg[i] : 0;
#pragma unroll
    for (int d = 1; d < 64; d <<= 1) v += __shfl_xor(v, d, 64);
    if (lane == 0) wsum[wid] = v;
    __syncthreads();
    if (tid == 0) {
        int s = 0;
#pragma unroll
        for (int j = 0; j < 16; ++j) s += wsum[j];
        bsum[blockIdx.x] = s;
    }
}

__global__ void scan2_kernel(const int* __restrict__ bsum, int* __restrict__ boff,
                             int* __restrict__ off) {
    int lane = threadIdx.x;  // launched with 64 threads
    int v0 = (lane < SNB) ? bsum[lane] : 0;
    int v  = v0;
#pragma unroll
    for (int d = 1; d < 64; d <<= 1) {
        int t = __shfl_up(v, d, 64);
        if (lane >= d) v += t;
    }
    if (lane < SNB) boff[lane] = v - v0;
    if (lane == SNB - 1) off[NN] = v;
}

__global__ __launch_bounds__(1024) void scan3_kernel(int* __restrict__ cur,
                                                     const int* __restrict__ boff,
                                                     int* __restrict__ off) {
    __shared__ int wsum[16];
    int tid = threadIdx.x, lane = tid & 63, wid = tid >> 6;
    int i  = blockIdx.x * 1024 + tid;
    int v0 = (i < NN) ? cur[i] : 0;
    int v  = v0;
#pragma unroll
    for (int d = 1; d < 64; d <<= 1) {
        int t = __shfl_up(v, d, 64);
        if (lane >= d) v += t;
    }
    if (lane == 63) wsum[wid] = v;
    __syncthreads();
    int wpre = 0;
#pragma unroll
    for (int j = 0; j < 16; ++j)
        if (j < wid) wpre += wsum[j];
    int excl = boff[blockIdx.x] + wpre + v - v0;
    if (i < NN) { off[i] = excl; cur[i] = excl; }
}

// ---------------- GEMM body (128x128 tile, BK=64, 4 waves, 16x16x32 bf16 MFMA) ----------

template <int K, int N>
__device__ __forceinline__ void gemm_body(const unsigned short* __restrict__ A,
                                          const unsigned short* __restrict__ BT,
                                          unsigned short* __restrict__ C,
                                          int M, int bx, int by) {
    __shared__ unsigned short As[128 * 64];
    __shared__ unsigned short Bs[128 * 64];

    const int tid  = threadIdx.x;
    const int lane = tid & 63;
    const int wid  = tid >> 6;
    const int wm   = wid >> 1;
    const int wn   = wid & 1;
    const int brow = bx * 128;
    const int bcol = by * 128;
    const int r15   = lane & 15;
    const int khalf = (lane >> 4) * 8;

    f32x4 acc[4][4] = {};

    for (int k0 = 0; k0 < K; k0 += 64) {
#pragma unroll
        for (int c = 0; c < 4; ++c) {
            int b   = wid * 4096 + c * 1024 + lane * 16;
            int row = b >> 7;
            int cby = (b & 127) ^ ((row & 7) << 4);
            const char* ga = (const char*)(A + (size_t)(brow + row) * K + k0) + cby;
            gload_lds16(ga, (char*)As + wid * 4096 + c * 1024);
            const char* gb = (const char*)(BT + (size_t)(bcol + row) * K + k0) + cby;
            gload_lds16(gb, (char*)Bs + wid * 4096 + c * 1024);
        }
        __syncthreads();

        bf16x8 af[4][2], bfr[4][2];
#pragma unroll
        for (int m = 0; m < 4; ++m) {
            int row = wm * 64 + m * 16 + r15;
            int rb  = row * 128;
            int sw  = (row & 7) << 4;
#pragma unroll
            for (int ks = 0; ks < 2; ++ks) {
                int byte = rb + (((ks * 32 + khalf) * 2) ^ sw);
                af[m][ks] = *(const bf16x8*)((const char*)As + byte);
            }
        }
#pragma unroll
        for (int n = 0; n < 4; ++n) {
            int row = wn * 64 + n * 16 + r15;
            int rb  = row * 128;
            int sw  = (row & 7) << 4;
#pragma unroll
            for (int ks = 0; ks < 2; ++ks) {
                int byte = rb + (((ks * 32 + khalf) * 2) ^ sw);
                bfr[n][ks] = *(const bf16x8*)((const char*)Bs + byte);
            }
        }
#pragma unroll
        for (int m = 0; m < 4; ++m)
#pragma unroll
            for (int n = 0; n < 4; ++n)
#pragma unroll
                for (int ks = 0; ks < 2; ++ks)
                    acc[m][n] = __builtin_amdgcn_mfma_f32_16x16x32_bf16(
                        af[m][ks], bfr[n][ks], acc[m][n], 0, 0, 0);
        __syncthreads();
    }

    const int crow0 = brow + wm * 64;
    const int ccol0 = bcol + wn * 64 + r15;
    const int rsub  = (lane >> 4) * 4;
#pragma unroll
    for (int m = 0; m < 4; ++m) {
#pragma unroll
        for (int r = 0; r < 4; ++r) {
            int grow = crow0 + m * 16 + rsub + r;
            if (grow < M) {
#pragma unroll
                for (int n = 0; n < 4; ++n)
                    C[(size_t)grow * N + ccol0 + n * 16] = f2bf(acc[m][n][r]);
            }
        }
    }
}

// ---------------- scatter body: 4 independent atomic+store chains, int2 payload -------

__device__ __forceinline__ void scatter_body(int bid,
                                             const int* __restrict__ src,
                                             const int* __restrict__ dst,
                                             const float* __restrict__ w,
                                             int* __restrict__ cur,
                                             int2* __restrict__ csr) {
    int t  = bid * 256 + threadIdx.x;
    int e3 = t + 3 * ESTRIDE;
    bool v3 = e3 < NE;  // e0..e2 always valid
    int   d0 = dst[t],           s0 = src[t];
    int   d1 = dst[t + ESTRIDE], s1 = src[t + ESTRIDE];
    int   d2 = dst[t + 2*ESTRIDE], s2 = src[t + 2*ESTRIDE];
    int   d3 = v3 ? dst[e3] : 0,  s3 = v3 ? src[e3] : 0;
    float w0 = w[t], w1 = w[t + ESTRIDE], w2 = w[t + 2*ESTRIDE];
    float w3 = v3 ? w[e3] : 0.f;
    int p0 = atomicAdd(&cur[d0], 1);
    int p1 = atomicAdd(&cur[d1], 1);
    int p2 = atomicAdd(&cur[d2], 1);
    int p3 = v3 ? atomicAdd(&cur[d3], 1) : 0;
    csr[p0] = make_int2(s0, __float_as_int(w0));
    csr[p1] = make_int2(s1, __float_as_int(w1));
    csr[p2] = make_int2(s2, __float_as_int(w2));
    if (v3) csr[p3] = make_int2(s3, __float_as_int(w3));
}

// ---------------- fused: gemm1 || scatter ----------------

__global__ __launch_bounds__(256) void fused_gemm1_scatter_kernel(
    const unsigned short* __restrict__ A, const unsigned short* __restrict__ BT,
    unsigned short* __restrict__ C,
    const int* __restrict__ src, const int* __restrict__ dst,
    const float* __restrict__ w, int* __restrict__ cur, int2* __restrict__ csr) {
    if (blockIdx.x < GEMM1_BLOCKS) {
        gemm_body<FIN, FHID>(A, BT, C, NN, blockIdx.x % 391, blockIdx.x / 391);
    } else {
        scatter_body(blockIdx.x - GEMM1_BLOCKS, src, dst, w, cur, csr);
    }
}

template <int K, int N>
__global__ __launch_bounds__(256) void gemm_bf16_kernel(const unsigned short* __restrict__ A,
                                                        const unsigned short* __restrict__ BT,
                                                        unsigned short* __restrict__ C,
                                                        int M) {
    gemm_body<K, N>(A, BT, C, M, blockIdx.x, blockIdx.y);
}

// ---------------- pull-SpMM: one wave per node, 8-wide predicated edge unroll ---------

template <int F, bool RELU, bool OUTBF>
__global__ __launch_bounds__(256) void spmm_kernel(const unsigned short* __restrict__ X,
                                                   const int* __restrict__ off,
                                                   const int2* __restrict__ csr,
                                                   void* __restrict__ Yv) {
    int gw   = (int)((blockIdx.x * 256 + threadIdx.x) >> 6);
    int lane = threadIdx.x & 63;
    if (gw >= NN) return;
    int e0 = off[gw];
    int e1 = off[gw + 1];

    if constexpr (F == 256) {
        float acc0 = 0.f, acc1 = 0.f, acc2 = 0.f, acc3 = 0.f;
        const size_t lo = (size_t)lane * 4;
        for (int e = e0; e < e1; e += 8) {
            int   ss[8];
            float ww[8];
#pragma unroll
            for (int j = 0; j < 8; ++j) {
                int  ee = e + j;
                bool v  = ee < e1;
                int2 sw = csr[v ? ee : e0];
                ss[j] = sw.x;
                ww[j] = v ? __int_as_float(sw.y) : 0.f;
            }
            u16x4 r[8];
#pragma unroll
            for (int j = 0; j < 8; ++j)
                r[j] = *(const u16x4*)(X + (size_t)ss[j] * F + lo);
#pragma unroll
            for (int j = 0; j < 8; ++j) {
                acc0 += ww[j] * bf2f(r[j][0]);
                acc1 += ww[j] * bf2f(r[j][1]);
                acc2 += ww[j] * bf2f(r[j][2]);
                acc3 += ww[j] * bf2f(r[j][3]);
            }
        }
        if (RELU) {
            acc0 = fmaxf(acc0, 0.f); acc1 = fmaxf(acc1, 0.f);
            acc2 = fmaxf(acc2, 0.f); acc3 = fmaxf(acc3, 0.f);
        }
        u16x4 o;
        o[0] = f2bf(acc0); o[1] = f2bf(acc1); o[2] = f2bf(acc2); o[3] = f2bf(acc3);
        *(u16x4*)((unsigned short*)Yv + (size_t)gw * F + lo) = o;
    } else {  // F == 128
        float acc0 = 0.f, acc1 = 0.f;
        const size_t lo = (size_t)lane * 2;
        for (int e = e0; e < e1; e += 8) {
            int   ss[8];
            float ww[8];
#pragma unroll
            for (int j = 0; j < 8; ++j) {
                int  ee = e + j;
                bool v  = ee < e1;
                int2 sw = csr[v ? ee : e0];
                ss[j] = sw.x;
                ww[j] = v ? __int_as_float(sw.y) : 0.f;
            }
            u16x2 r[8];
#pragma unroll
            for (int j = 0; j < 8; ++j)
                r[j] = *(const u16x2*)(X + (size_t)ss[j] * F + lo);
#pragma unroll
            for (int j = 0; j < 8; ++j) {
                acc0 += ww[j] * bf2f(r[j][0]);
                acc1 += ww[j] * bf2f(r[j][1]);
            }
        }
        if (RELU) { acc0 = fmaxf(acc0, 0.f); acc1 = fmaxf(acc1, 0.f); }
        float2 o = make_float2(acc0, acc1);
        *(float2*)((float*)Yv + (size_t)gw * F + lo) = o;
    }
}

// ---------------- launch ----------------

extern "C" void kernel_launch(void* const* d_in, const int* in_sizes, int n_in,
                              void* d_out, int out_size, void* d_ws, size_t ws_size,
                              hipStream_t stream) {
    const float* features = (const float*)d_in[0];
    const int*   edge_src = (const int*)d_in[1];
    const int*   edge_dst = (const int*)d_in[2];
    const float* edge_w   = (const float*)d_in[3];
    const float* W1       = (const float*)d_in[4];
    const float* W2       = (const float*)d_in[5];
    float* out = (float*)d_out;

    char*  ws  = (char*)d_ws;
    size_t ofs = 0;
    auto carve = [&](size_t bytes) -> void* {
        void* r = ws + ofs;
        ofs = (ofs + bytes + 255) & ~(size_t)255;
        return r;
    };
    int*            off   = (int*)carve((NN + 1) * sizeof(int));
    int*            cur   = (int*)carve(NN * sizeof(int));
    int*            bsum  = (int*)carve(SNB * sizeof(int));
    int*            boff  = (int*)carve((SNB + 1) * sizeof(int));
    int2*           csr   = (int2*)carve((size_t)NE * sizeof(int2));
    unsigned short* Xb    = (unsigned short*)carve((size_t)MPAD * FIN * 2);
    unsigned short* W1T   = (unsigned short*)carve((size_t)FHID * FIN * 2);
    unsigned short* W2T   = (unsigned short*)carve((size_t)FOUT * FHID * 2);
    unsigned short* H0b   = (unsigned short*)carve((size_t)MPAD * FHID * 2);
    unsigned short* Hb    = (unsigned short*)carve((size_t)MPAD * FHID * 2);
    unsigned short* H1b   = H0b;  // H0b dead after spmm1

    hipMemsetAsync(cur, 0, NN * sizeof(int), stream);

    // cast_x || count_deg || transpose W1 || transpose W2
    fused_pre_kernel<<<CAST_BLOCKS + CNT_BLOCKS + TW1_BLOCKS + TW2_BLOCKS, 256, 0, stream>>>(
        features, Xb, edge_dst, cur, W1, W1T, W2, W2T);

    // decoupled scan: deg -> off (and cursor copy in cur)
    scan1_kernel<<<SNB, 1024, 0, stream>>>(cur, bsum);
    scan2_kernel<<<1, 64, 0, stream>>>(bsum, boff, off);
    scan3_kernel<<<SNB, 1024, 0, stream>>>(cur, boff, off);

    // gemm1 (H0 = X @ W1) || scatter (CSR fill)
    fused_gemm1_scatter_kernel<<<GEMM1_BLOCKS + SCAT_BLOCKS, 256, 0, stream>>>(
        Xb, W1T, H0b, edge_src, edge_dst, edge_w, cur, csr);

    // hidden = relu(A @ H0)  (bf16)
    spmm_kernel<FHID, true, true><<<12500, 256, 0, stream>>>(H0b, off, csr, Hb);

    // H1 = hidden @ W2 ; out = A @ H1
    gemm_bf16_kernel<FHID, FOUT><<<dim3(391, 1), 256, 0, stream>>>(Hb, W2T, H1b, NN);
    spmm_kernel<FOUT, false, false><<<12500, 256, 0, stream>>>(H1b, off, csr, out);
}